// Round 5
// baseline (396.477 us; speedup 1.0000x reference)
//
#include <hip/hip_runtime.h>
#include <stdint.h>

// B=8, C=128, N=4096 (64x64), GROUPS=8 (16 ch/group)
// Split-KV flash attention, 32x32x16 MFMA quadrants, max-free base-2 softmax.
// R14 = R13 + two changes in k_attn_part only:
//   (1) T14 async-STAGE: K(t+1)/V(t+1) prefetched into regs right after
//       barrier B of iter t (latency hides under QK+softmax+PV); only
//       ds_writes remain at the top of t+1. VGPR headroom exists now (R13
//       freed lacc; 68 -> ~140 expected, cap 170 at (256,3)).
//   (2) P pack via v_cvt_pk_bf16_f32 (1 op / 2 values) instead of manual
//       3-op RNE f2bf (P is positive+bounded; rounding change harmless,
//       verified passing in R2's run).
// R13 lesson kept: ones-MFMA row-sum replaced by VALU l_run + epilogue
// shfl/LDS combine. R10-12 lesson kept: no full-C accumulators, no
// runtime-indexed ext_vector arrays (rule #20).

typedef __attribute__((ext_vector_type(8))) short short8;
typedef __attribute__((ext_vector_type(4))) float f32x4;
typedef __attribute__((ext_vector_type(16))) float f32x16;

#define MFMA_BF16(a, b, c) __builtin_amdgcn_mfma_f32_16x16x32_bf16((a), (b), (c), 0, 0, 0)
#define MFMA32(a, b, c) __builtin_amdgcn_mfma_f32_32x32x16_bf16((a), (b), (c), 0, 0, 0)
#define EXP2(x) __builtin_amdgcn_exp2f(x)

// (1/sqrt(128)) * log2(e) — folded into Q at k_qkv store time (softmax runs in base 2)
#define QSCALE 0.12751743f

__device__ __forceinline__ unsigned short f2bf(float f) {
    unsigned int u = __builtin_bit_cast(unsigned int, f);
    u += 0x7FFFu + ((u >> 16) & 1u);   // RNE (finite values only)
    return (unsigned short)(u >> 16);
}
__device__ __forceinline__ float bf2f(unsigned int lo16) {
    return __builtin_bit_cast(float, lo16 << 16);
}
__device__ __forceinline__ short8 ldg8(const unsigned short* p) {
    return __builtin_bit_cast(short8, *(const uint4*)p);
}
__device__ __forceinline__ unsigned int cvtpk(float lo, float hi) {
    unsigned int r;
    asm("v_cvt_pk_bf16_f32 %0, %1, %2" : "=v"(r) : "v"(lo), "v"(hi));
    return r;
}

// ---------------- Kernel 1: GroupNorm partial sums (atomic) + weight bf16 conv ------
__global__ __launch_bounds__(256) void k_pre(const float* __restrict__ x,
                                             float* __restrict__ sums,
                                             const float* __restrict__ qkv_w,
                                             const float* __restrict__ proj_w,
                                             unsigned short* __restrict__ wq,
                                             unsigned short* __restrict__ wp) {
    if (blockIdx.x >= 1024) {            // weight conversion: 64 blocks x 1024 elems
        int i = ((blockIdx.x - 1024) * 256 + threadIdx.x) * 4;
        const float* src; unsigned short* dst; int off;
        if (i < 49152) { src = qkv_w; dst = wq; off = i; }
        else           { src = proj_w; dst = wp; off = i - 49152; }
        float4 v = *(const float4*)(src + off);
        uint2 pk;
        pk.x = (unsigned int)f2bf(v.x) | ((unsigned int)f2bf(v.y) << 16);
        pk.y = (unsigned int)f2bf(v.z) | ((unsigned int)f2bf(v.w) << 16);
        *(uint2*)(dst + off) = pk;
        return;
    }
    int g     = blockIdx.x >> 4;         // 0..63 (b*8+gr); group slab contiguous
    int slice = blockIdx.x & 15;
    const float* p = x + (size_t)g * 65536 + slice * 4096;
    float s = 0.f, sq = 0.f;
#pragma unroll
    for (int i = 0; i < 4; ++i) {
        float4 v = *(const float4*)(p + threadIdx.x * 4 + i * 1024);
        s  += v.x + v.y + v.z + v.w;
        sq += v.x*v.x + v.y*v.y + v.z*v.z + v.w*v.w;
    }
#pragma unroll
    for (int m = 1; m < 64; m <<= 1) { s += __shfl_xor(s, m, 64); sq += __shfl_xor(sq, m, 64); }
    __shared__ float ss[4], ssq[4];
    int w = threadIdx.x >> 6;
    if ((threadIdx.x & 63) == 0) { ss[w] = s; ssq[w] = sq; }
    __syncthreads();
    if (threadIdx.x == 0) {
        atomicAdd(&sums[g * 2],     ss[0] + ss[1] + ss[2] + ss[3]);
        atomicAdd(&sums[g * 2 + 1], ssq[0] + ssq[1] + ssq[2] + ssq[3]);
    }
}

// ---------------- Kernel 2: fused GroupNorm-apply + QKV GEMM ----------------
// Q (pre-scaled by QSCALE), K as bf16 [b][n][c]; V as bf16 [b][c][n].
// V tiles computed transposed (MFMA(bfrag, af) -> D[n][c]) -> packed 8B global stores.
__global__ __launch_bounds__(256) void k_qkv(const float* __restrict__ x,
                                             const float* __restrict__ sums,
                                             const float* __restrict__ gn_w,
                                             const float* __restrict__ gn_b,
                                             const unsigned short* __restrict__ wq,
                                             const float* __restrict__ qkv_b,
                                             unsigned short* __restrict__ q_ws,
                                             unsigned short* __restrict__ k_ws,
                                             unsigned short* __restrict__ v_ws) {
    __shared__ unsigned short h_lds[64][136];   // [n][c], +8 pad
    const int tid  = threadIdx.x;
    const int b    = blockIdx.x >> 6;
    const int n0   = (blockIdx.x & 63) << 6;
    const int lane = tid & 63, wave = tid >> 6;
    const int l15  = lane & 15, q4 = lane >> 4;

    // normalize x tile -> bf16 -> h_lds[n][c]
    {
        int cb = tid >> 4;            // 0..15
        int nn = (tid & 15) << 2;     // 0..60
#pragma unroll
        for (int k = 0; k < 8; ++k) {
            int c = cb + (k << 4);
            float4 v = *(const float4*)(x + ((size_t)(b * 128 + c) << 12) + n0 + nn);
            int g = c >> 4;
            float ts = sums[(b * 8 + g) * 2];
            float tq = sums[(b * 8 + g) * 2 + 1];
            float mean = ts * (1.f / 65536.f);
            float var  = tq * (1.f / 65536.f) - mean * mean;
            float rstd = rsqrtf(var + 1e-5f);
            float ga = gn_w[c] * rstd;
            float be = gn_b[c] - mean * ga;
            h_lds[nn + 0][c] = f2bf(v.x * ga + be);
            h_lds[nn + 1][c] = f2bf(v.y * ga + be);
            h_lds[nn + 2][c] = f2bf(v.z * ga + be);
            h_lds[nn + 3][c] = f2bf(v.w * ga + be);
        }
    }
    __syncthreads();

    short8 bfrag[4][4];               // h[n][c]: as B (k=c, n=l15) or as A (m=n, k=c)
#pragma unroll
    for (int nt = 0; nt < 4; ++nt)
#pragma unroll
        for (int ks = 0; ks < 4; ++ks)
            bfrag[nt][ks] = *(const short8*)&h_lds[nt * 16 + l15][ks * 32 + q4 * 8];

#pragma unroll
    for (int ot = 0; ot < 6; ++ot) {
        int o0 = wave * 96 + ot * 16;                 // 16-row tile is purely Q, K, or V
        short8 af[4];                                 // w[o][c]: as A (m=o) or as B (n=o)
#pragma unroll
        for (int ks = 0; ks < 4; ++ks)
            af[ks] = ldg8(wq + (size_t)(o0 + l15) * 128 + ks * 32 + q4 * 8);

        if (o0 < 256) {               // Q or K: D[row=o(reg)][col=n=l15] -> [n][c] layout
            float bias[4];
#pragma unroll
            for (int r = 0; r < 4; ++r) bias[r] = qkv_b[o0 + q4 * 4 + r];
            float qs = (o0 < 128) ? QSCALE : 1.0f;
#pragma unroll
            for (int nt = 0; nt < 4; ++nt) {
                f32x4 acc = {0.f, 0.f, 0.f, 0.f};
#pragma unroll
                for (int ks = 0; ks < 4; ++ks)
                    acc = MFMA_BF16(af[ks], bfrag[nt][ks], acc);
                int n = n0 + nt * 16 + l15;
                unsigned short* dst = (o0 < 128) ? q_ws : k_ws;
                int oo = (o0 < 128) ? o0 : (o0 - 128);
                unsigned int lo = (unsigned int)f2bf((acc[0] + bias[0]) * qs) |
                                  ((unsigned int)f2bf((acc[1] + bias[1]) * qs) << 16);
                unsigned int hi = (unsigned int)f2bf((acc[2] + bias[2]) * qs) |
                                  ((unsigned int)f2bf((acc[3] + bias[3]) * qs) << 16);
                uint2 pk; pk.x = lo; pk.y = hi;
                *(uint2*)&dst[((size_t)(b * 4096 + n) << 7) + oo + q4 * 4] = pk;
            }
        } else {                      // V transposed: D[row=n(reg)][col=c=l15] -> [c][n]
            int c = o0 - 256 + l15;
            float vb = qkv_b[o0 + l15];
            unsigned short* vrow = v_ws + ((size_t)(b * 128 + c) << 12) + n0;
#pragma unroll
            for (int nt = 0; nt < 4; ++nt) {
                f32x4 acc = {0.f, 0.f, 0.f, 0.f};
#pragma unroll
                for (int ks = 0; ks < 4; ++ks)
                    acc = MFMA_BF16(bfrag[nt][ks], af[ks], acc);
                // n = nt*16 + q4*4 + r (4 consecutive) at fixed c -> packed 8B store
                unsigned int lo = (unsigned int)f2bf(acc[0] + vb) |
                                  ((unsigned int)f2bf(acc[1] + vb) << 16);
                unsigned int hi = (unsigned int)f2bf(acc[2] + vb) |
                                  ((unsigned int)f2bf(acc[3] + vb) << 16);
                uint2 pk; pk.x = lo; pk.y = hi;
                *(uint2*)&vrow[nt * 16 + q4 * 4] = pk;
            }
        }
    }
}

// ---------------- Kernel 3: flash attention partial (split-KV, 32x32 quadrants) ----
// block = 256 threads / 4 waves = (b, i-tile, chunk); chunk covers 1024 j.
// QK computes S^T: MFMA(A=kf, B=qf) -> D[j(reg)][i(lane)], so P writes are 4 packed
// b64 per wave-quadrant into P_lds[i][j]. PV reads (A=P[i][j], B=V^T) unchanged.
// R14: K/V for iter t+1 prefetched into regs during compute of t (T14 split):
//      issue global loads right after barrier B; ds_write them after barrier A
//      of t+1. Loads' ~300-500cy latency hides under QK+softmax+PV.
//      P pack via v_cvt_pk_bf16_f32 (8 ops vs ~45 manual f2bf ops per iter).
__global__ __launch_bounds__(256, 3) void k_attn_part(const unsigned short* __restrict__ q_ws,
                                                      const unsigned short* __restrict__ k_ws,
                                                      const unsigned short* __restrict__ v_ws,
                                                      unsigned short* __restrict__ o_part,
                                                      float* __restrict__ ml) {
    __shared__ unsigned short K_lds[64][136];   // [j][c], +8 pad   (17408 B)
    __shared__ unsigned short V_lds[128][72];   // [c][j], +8 pad   (18432 B)
    __shared__ unsigned short P_lds[64][72];    // [i][j], +8 pad   ( 9216 B)
    __shared__ float Lp[128];                   // [jh*64 + i] row-sum exchange (512 B)

    const int tid   = threadIdx.x;
    const int chunk = blockIdx.x & 3;
    const int tile  = (blockIdx.x >> 2) & 63;
    const int b     = blockIdx.x >> 8;
    const int i0    = tile << 6;
    const int lane  = tid & 63, wave = tid >> 6;
    const int ih    = wave >> 1, jh = wave & 1;   // jh doubles as c-half in PV
    const int l31   = lane & 31, h = lane >> 5;

    // Q frags (pre-scaled by QSCALE): lane holds i=l31, k=c=ks*16+h*8+e
    short8 qf[8];
    {
        const unsigned short* qp =
            q_ws + ((size_t)(b * 4096 + i0 + ih * 32 + l31) << 7) + h * 8;
#pragma unroll
        for (int ks = 0; ks < 8; ++ks) qf[ks] = ldg8(qp + ks * 16);
    }

    f32x16 acc[2];                           // O[i(reg)][c = jh*64 + ct*32 + l31]
#pragma unroll
    for (int e = 0; e < 16; ++e) { acc[0][e] = 0.f; acc[1][e] = 0.f; }
    float l_run = 0.f;                       // this lane's 16-j partial per iter

    const unsigned short* kbase = k_ws + ((size_t)b << 19);
    const unsigned short* vsrc  = v_ws + ((size_t)b << 19) +
                                  ((size_t)(tid >> 1) << 12) + (tid & 1) * 32;

    // prologue: prefetch tile 0 into regs
    uint4 kreg[4], vreg[4];
    {
        const unsigned short* ksrc = kbase + ((size_t)(chunk << 10) << 7);
#pragma unroll
        for (int i = 0; i < 4; ++i) kreg[i] = *(const uint4*)(ksrc + (i * 256 + tid) * 8);
        const unsigned short* vp = vsrc + (chunk << 10);
#pragma unroll
        for (int k = 0; k < 4; ++k) vreg[k] = *(const uint4*)(vp + k * 8);
    }

    for (int it = 0; it < 16; ++it) {
        __syncthreads();                      // A: prev iter's K/V/P reads done
        {   // ds_write staged K tile from regs: chunk f=i*256+tid -> [row][136-pitch]
#pragma unroll
            for (int i = 0; i < 4; ++i) {
                int f = i * 256 + tid;        // 0..1023 16B-chunks
                int row = f >> 4, q = (f & 15) << 3;
                *(uint4*)&K_lds[row][q] = kreg[i];
            }
            // ds_write staged V tile [128 c][72-pitch j]
            uint4* vd = (uint4*)&V_lds[tid >> 1][(tid & 1) * 32];
#pragma unroll
            for (int k = 0; k < 4; ++k) vd[k] = vreg[k];
        }
        __syncthreads();                      // B: K, V visible

        if (it < 15) {                        // prefetch next tile; latency hides
            int j1 = (chunk << 10) + ((it + 1) << 6);
            const unsigned short* ksrc = kbase + ((size_t)j1 << 7);
#pragma unroll
            for (int i = 0; i < 4; ++i) kreg[i] = *(const uint4*)(ksrc + (i * 256 + tid) * 8);
            const unsigned short* vp = vsrc + j1;
#pragma unroll
            for (int k = 0; k < 4; ++k) vreg[k] = *(const uint4*)(vp + k * 8);
        }

        // S^T quadrant = K Q^T : D row = j = (r&3)+8(r>>2)+4h (in jh half),
        //                        col = i = l31 (in ih half)
        f32x16 s;
#pragma unroll
        for (int e = 0; e < 16; ++e) s[e] = 0.f;
#pragma unroll
        for (int ks = 0; ks < 8; ++ks) {
            short8 kf = *(const short8*)&K_lds[jh * 32 + l31][ks * 16 + h * 8];
            s = MFMA32(kf, qf[ks], s);
        }

        // max-free softmax: p = exp2(min(s,30)); VALU row-sum partial into l_run;
        // packed b64 writes into P_lds[i][j] via cvt_pk
        float pv[16];
#pragma unroll
        for (int e = 0; e < 16; ++e) pv[e] = EXP2(fminf(s[e], 30.f));
        l_run += (((pv[0] + pv[1]) + (pv[2] + pv[3])) +
                  ((pv[4] + pv[5]) + (pv[6] + pv[7]))) +
                 (((pv[8] + pv[9]) + (pv[10] + pv[11])) +
                  ((pv[12] + pv[13]) + (pv[14] + pv[15])));
        unsigned short* prow = &P_lds[ih * 32 + l31][jh * 32 + (h << 2)];
#pragma unroll
        for (int rr = 0; rr < 4; ++rr) {
            uint2 pk;
            pk.x = cvtpk(pv[rr * 4 + 0], pv[rr * 4 + 1]);
            pk.y = cvtpk(pv[rr * 4 + 2], pv[rr * 4 + 3]);
            *(uint2*)(prow + rr * 8) = pk;
        }
        __syncthreads();                      // C: V + P visible

        // O += P V^T   (A = P[i][j], B = V^T[j][c])
#pragma unroll
        for (int ks = 0; ks < 4; ++ks) {
            short8 pf = *(const short8*)&P_lds[ih * 32 + l31][ks * 16 + h * 8];
#pragma unroll
            for (int ct = 0; ct < 2; ++ct) {
                short8 vf = *(const short8*)&V_lds[jh * 64 + ct * 32 + l31][ks * 16 + h * 8];
                acc[ct] = MFMA32(pf, vf, acc[ct]);
            }
        }
    }

    // epilogue: combine row sums (h via shfl, jh via LDS), normalize, store
    float l2 = l_run + __shfl_xor(l_run, 32);
    // lane (l31,h) covers j = {jh*32 + rr*8 + 4h + q} over 16 regs — h=0 and h=1
    // cover disjoint j sets of the same column i=l31; their sum = this wave's
    // full 32-j contribution for row i.  (shfl_xor(32) pairs h-halves at same l31)
    if (h == 0) Lp[jh * 64 + ih * 32 + l31] = l2;
    __syncthreads();

    size_t pbase = (size_t)((b * 64 + tile) * 4 + chunk) * 8192;
    float rl[16];
#pragma unroll
    for (int r = 0; r < 16; ++r) {
        int il = (r & 3) + ((r >> 2) << 3) + (h << 2);
        rl[r] = 1.0f / (Lp[ih * 32 + il] + Lp[64 + ih * 32 + il]);
    }
#pragma unroll
    for (int ct = 0; ct < 2; ++ct)
#pragma unroll
        for (int r = 0; r < 16; ++r) {
            int row = ih * 32 + (r & 3) + ((r >> 2) << 3) + (h << 2);
            o_part[pbase + (size_t)row * 128 + jh * 64 + ct * 32 + l31] =
                f2bf(acc[ct][r] * rl[r]);
        }
    if (tid < 64) {
        int mb = ((b * 64 + tile) * 4 + chunk) * 64;
        ml[mb + tid] = __log2f(Lp[tid] + Lp[64 + tid]);
    }
}

// ---------------- Kernel 4: merge partials + proj GEMM + bias + residual ----------
__global__ __launch_bounds__(256) void k_merge_proj(const unsigned short* __restrict__ o_part,
                                                    const float* __restrict__ ml,
                                                    const float* __restrict__ x,
                                                    const unsigned short* __restrict__ wp,
                                                    const float* __restrict__ proj_b,
                                                    float* __restrict__ out) {
    __shared__ unsigned short O_lds[64][136];
    __shared__ float wgt[64][4];
    const int tid  = threadIdx.x;
    const int b    = blockIdx.x >> 6;
    const int tile = blockIdx.x & 63;
    const int i0   = tile << 6;
    const int lane = tid & 63, wave = tid >> 6;
    const int l15  = lane & 15, q4 = lane >> 4;
    const int tb   = (b * 64 + tile) * 4;

    if (tid < 64) {
        float m0 = ml[(tb + 0) * 64 + tid], m1 = ml[(tb + 1) * 64 + tid];
        float m2 = ml[(tb + 2) * 64 + tid], m3 = ml[(tb + 3) * 64 + tid];
        float M = fmaxf(fmaxf(m0, m1), fmaxf(m2, m3));
        float w0 = EXP2(m0 - M), w1 = EXP2(m1 - M), w2 = EXP2(m2 - M), w3 = EXP2(m3 - M);
        float rW = 1.0f / (w0 + w1 + w2 + w3);
        wgt[tid][0] = w0 * rW; wgt[tid][1] = w1 * rW;
        wgt[tid][2] = w2 * rW; wgt[tid][3] = w3 * rW;
    }
    __syncthreads();

    {   // weighted merge: thread t -> row n=t>>2, 32-c quarter q=t&3
        int n = tid >> 2, q = tid & 3;
        float w[4];
#pragma unroll
        for (int ch = 0; ch < 4; ++ch) w[ch] = wgt[n][ch];
#pragma unroll
        for (int g = 0; g < 4; ++g) {             // 8 c per group
            float acc[8];
#pragma unroll
            for (int e = 0; e < 8; ++e) acc[e] = 0.f;
#pragma unroll
            for (int ch = 0; ch < 4; ++ch) {
                const unsigned short* p =
                    o_part + (size_t)(tb + ch) * 8192 + (size_t)n * 128 + q * 32 + g * 8;
                uint4 v = *(const uint4*)p;
                float wc = w[ch];
                acc[0] += wc * bf2f(v.x & 0xFFFF); acc[1] += wc * bf2f(v.x >> 16);
                acc[2] += wc * bf2f(v.y & 0xFFFF); acc[3] += wc * bf2f(v.y >> 16);
                acc[4] += wc * bf2f(v.z & 0xFFFF); acc[5] += wc * bf2f(v.z >> 16);
                acc[6] += wc * bf2f(v.w & 0xFFFF); acc[7] += wc * bf2f(v.w >> 16);
            }
            uint4 pk;
            pk.x = (unsigned int)f2bf(acc[0]) | ((unsigned int)f2bf(acc[1]) << 16);
            pk.y = (unsigned int)f2bf(acc[2]) | ((unsigned int)f2bf(acc[3]) << 16);
            pk.z = (unsigned int)f2bf(acc[4]) | ((unsigned int)f2bf(acc[5]) << 16);
            pk.w = (unsigned int)f2bf(acc[6]) | ((unsigned int)f2bf(acc[7]) << 16);
            *(uint4*)&O_lds[n][q * 32 + g * 8] = pk;
        }
    }
    __syncthreads();

    // proj GEMM: out[o][n] = sum_c proj_w[o][c] * O[n][c] + proj_b + x
    short8 bfrag[4][4];
#pragma unroll
    for (int nt = 0; nt < 4; ++nt)
#pragma unroll
        for (int ks = 0; ks < 4; ++ks)
            bfrag[nt][ks] = *(const short8*)&O_lds[nt * 16 + l15][ks * 32 + q4 * 8];

#pragma unroll
    for (int ot = 0; ot < 2; ++ot) {
        int o0 = wave * 32 + ot * 16;
        short8 af[4];
#pragma unroll
        for (int ks = 0; ks < 4; ++ks)
            af[ks] = ldg8(wp + (size_t)(o0 + l15) * 128 + ks * 32 + q4 * 8);
        float pb[4];
#pragma unroll
        for (int r = 0; r < 4; ++r) pb[r] = proj_b[o0 + q4 * 4 + r];

#pragma unroll
        for (int nt = 0; nt < 4; ++nt) {
            f32x4 acc = {0.f, 0.f, 0.f, 0.f};
#pragma unroll
            for (int ks = 0; ks < 4; ++ks)
                acc = MFMA_BF16(af[ks], bfrag[nt][ks], acc);
#pragma unroll
            for (int r = 0; r < 4; ++r) {
                size_t idx = ((size_t)(b * 128 + o0 + q4 * 4 + r) << 12) + i0 + nt * 16 + l15;
                out[idx] = x[idx] + acc[r] + pb[r];
            }
        }
    }
}

// ---------------- launch ----------------
extern "C" void kernel_launch(void* const* d_in, const int* in_sizes, int n_in,
                              void* d_out, int out_size, void* d_ws, size_t ws_size,
                              hipStream_t stream) {
    const float* x      = (const float*)d_in[0];
    const float* gn_w   = (const float*)d_in[1];
    const float* gn_b   = (const float*)d_in[2];
    const float* qkv_w  = (const float*)d_in[3];
    const float* qkv_b  = (const float*)d_in[4];
    const float* proj_w = (const float*)d_in[5];
    const float* proj_b = (const float*)d_in[6];
    float* out = (float*)d_out;

    char* ws = (char*)d_ws;
    float* sums           = (float*)ws;                              // 512 B (zeroed below)
    unsigned short* wq    = (unsigned short*)(ws + 4096);            // 96 KB
    unsigned short* wp    = (unsigned short*)(ws + 4096 + 98304);    // 32 KB
    unsigned short* q_ws  = (unsigned short*)(ws + ((size_t)1  << 20));  // 8 MB
    unsigned short* k_ws  = (unsigned short*)(ws + ((size_t)9  << 20));  // 8 MB
    unsigned short* v_ws  = (unsigned short*)(ws + ((size_t)17 << 20));  // 8 MB
    unsigned short* o_part= (unsigned short*)(ws + ((size_t)25 << 20));  // 32 MB
    float* ml             = (float*)(ws + ((size_t)57 << 20));           // 512 KB

    hipMemsetAsync(sums, 0, 512, stream);
    k_pre<<<1088, 256, 0, stream>>>(x, sums, qkv_w, proj_w, wq, wp);
    k_qkv<<<512, 256, 0, stream>>>(x, sums, gn_w, gn_b, wq, qkv_b, q_ws, k_ws, v_ws);
    k_attn_part<<<2048, 256, 0, stream>>>(q_ws, k_ws, v_ws, o_part, ml);
    k_merge_proj<<<512, 256, 0, stream>>>(o_part, ml, x, wp, proj_b, out);
}

// Round 6
// 208.259 us; speedup vs baseline: 1.9038x; 1.9038x over previous
//
#include <hip/hip_runtime.h>
#include <stdint.h>

// B=8, C=128, N=4096 (64x64), GROUPS=8 (16 ch/group)
// Split-KV flash attention, 32x32x16 MFMA quadrants, max-free base-2 softmax.
// R15: staging via global_load_lds into DOUBLE-BUFFERED LDS for both K and V.
//      Register prefetch is dead (r5/r6, R10-12, R14: hipcc spills bulk regs
//      held across MFMA regions -> 543 MB scratch in R14). gload_lds uses no
//      registers; prefetch for tile t+1 issues right after barrier A of t, so
//      the vmcnt(0) inside the NEXT __syncthreads comes a full compute phase
//      later (L2 latency ~200-400cy < compute ~500cy -> drain ~free).
//      K: linear [64][128], XOR-16 slot swizzle via pre-swizzled global source
//         (verified R2/R3: 0 bank conflicts, correct).
//      V: linear [128][64], XOR-8 slot swizzle, same source-side trick.
//      2 barriers/iter (was 3); staging phase eliminated.
//      LDS 73.5 KB -> 2 blocks/CU (ILP replaces TLP); launch_bounds (256,2).
//      Compute layout identical to R13 (P_lds path, acc[2] c-half, VALU l_run).

typedef __attribute__((ext_vector_type(8))) short short8;
typedef __attribute__((ext_vector_type(4))) float f32x4;
typedef __attribute__((ext_vector_type(16))) float f32x16;

#define MFMA_BF16(a, b, c) __builtin_amdgcn_mfma_f32_16x16x32_bf16((a), (b), (c), 0, 0, 0)
#define MFMA32(a, b, c) __builtin_amdgcn_mfma_f32_32x32x16_bf16((a), (b), (c), 0, 0, 0)
#define EXP2(x) __builtin_amdgcn_exp2f(x)

// (1/sqrt(128)) * log2(e) — folded into Q at k_qkv store time (softmax runs in base 2)
#define QSCALE 0.12751743f

__device__ __forceinline__ unsigned short f2bf(float f) {
    unsigned int u = __builtin_bit_cast(unsigned int, f);
    u += 0x7FFFu + ((u >> 16) & 1u);   // RNE (finite values only)
    return (unsigned short)(u >> 16);
}
__device__ __forceinline__ float bf2f(unsigned int lo16) {
    return __builtin_bit_cast(float, lo16 << 16);
}
__device__ __forceinline__ short8 ldg8(const unsigned short* p) {
    return __builtin_bit_cast(short8, *(const uint4*)p);
}
__device__ __forceinline__ unsigned int cvtpk(float lo, float hi) {
    unsigned int r;
    asm("v_cvt_pk_bf16_f32 %0, %1, %2" : "=v"(r) : "v"(lo), "v"(hi));
    return r;
}
__device__ __forceinline__ void gload16(const void* g, void* l) {
    __builtin_amdgcn_global_load_lds(
        (__attribute__((address_space(1))) void*)g,
        (__attribute__((address_space(3))) void*)l, 16, 0, 0);
}

// ---------------- Kernel 1: GroupNorm partial sums (atomic) + weight bf16 conv ------
__global__ __launch_bounds__(256) void k_pre(const float* __restrict__ x,
                                             float* __restrict__ sums,
                                             const float* __restrict__ qkv_w,
                                             const float* __restrict__ proj_w,
                                             unsigned short* __restrict__ wq,
                                             unsigned short* __restrict__ wp) {
    if (blockIdx.x >= 1024) {            // weight conversion: 64 blocks x 1024 elems
        int i = ((blockIdx.x - 1024) * 256 + threadIdx.x) * 4;
        const float* src; unsigned short* dst; int off;
        if (i < 49152) { src = qkv_w; dst = wq; off = i; }
        else           { src = proj_w; dst = wp; off = i - 49152; }
        float4 v = *(const float4*)(src + off);
        uint2 pk;
        pk.x = (unsigned int)f2bf(v.x) | ((unsigned int)f2bf(v.y) << 16);
        pk.y = (unsigned int)f2bf(v.z) | ((unsigned int)f2bf(v.w) << 16);
        *(uint2*)(dst + off) = pk;
        return;
    }
    int g     = blockIdx.x >> 4;         // 0..63 (b*8+gr); group slab contiguous
    int slice = blockIdx.x & 15;
    const float* p = x + (size_t)g * 65536 + slice * 4096;
    float s = 0.f, sq = 0.f;
#pragma unroll
    for (int i = 0; i < 4; ++i) {
        float4 v = *(const float4*)(p + threadIdx.x * 4 + i * 1024);
        s  += v.x + v.y + v.z + v.w;
        sq += v.x*v.x + v.y*v.y + v.z*v.z + v.w*v.w;
    }
#pragma unroll
    for (int m = 1; m < 64; m <<= 1) { s += __shfl_xor(s, m, 64); sq += __shfl_xor(sq, m, 64); }
    __shared__ float ss[4], ssq[4];
    int w = threadIdx.x >> 6;
    if ((threadIdx.x & 63) == 0) { ss[w] = s; ssq[w] = sq; }
    __syncthreads();
    if (threadIdx.x == 0) {
        atomicAdd(&sums[g * 2],     ss[0] + ss[1] + ss[2] + ss[3]);
        atomicAdd(&sums[g * 2 + 1], ssq[0] + ssq[1] + ssq[2] + ssq[3]);
    }
}

// ---------------- Kernel 2: fused GroupNorm-apply + QKV GEMM ----------------
// Q (pre-scaled by QSCALE), K as bf16 [b][n][c]; V as bf16 [b][c][n].
// V tiles computed transposed (MFMA(bfrag, af) -> D[n][c]) -> packed 8B global stores.
__global__ __launch_bounds__(256) void k_qkv(const float* __restrict__ x,
                                             const float* __restrict__ sums,
                                             const float* __restrict__ gn_w,
                                             const float* __restrict__ gn_b,
                                             const unsigned short* __restrict__ wq,
                                             const float* __restrict__ qkv_b,
                                             unsigned short* __restrict__ q_ws,
                                             unsigned short* __restrict__ k_ws,
                                             unsigned short* __restrict__ v_ws) {
    __shared__ unsigned short h_lds[64][136];   // [n][c], +8 pad
    const int tid  = threadIdx.x;
    const int b    = blockIdx.x >> 6;
    const int n0   = (blockIdx.x & 63) << 6;
    const int lane = tid & 63, wave = tid >> 6;
    const int l15  = lane & 15, q4 = lane >> 4;

    // normalize x tile -> bf16 -> h_lds[n][c]
    {
        int cb = tid >> 4;            // 0..15
        int nn = (tid & 15) << 2;     // 0..60
#pragma unroll
        for (int k = 0; k < 8; ++k) {
            int c = cb + (k << 4);
            float4 v = *(const float4*)(x + ((size_t)(b * 128 + c) << 12) + n0 + nn);
            int g = c >> 4;
            float ts = sums[(b * 8 + g) * 2];
            float tq = sums[(b * 8 + g) * 2 + 1];
            float mean = ts * (1.f / 65536.f);
            float var  = tq * (1.f / 65536.f) - mean * mean;
            float rstd = rsqrtf(var + 1e-5f);
            float ga = gn_w[c] * rstd;
            float be = gn_b[c] - mean * ga;
            h_lds[nn + 0][c] = f2bf(v.x * ga + be);
            h_lds[nn + 1][c] = f2bf(v.y * ga + be);
            h_lds[nn + 2][c] = f2bf(v.z * ga + be);
            h_lds[nn + 3][c] = f2bf(v.w * ga + be);
        }
    }
    __syncthreads();

    short8 bfrag[4][4];               // h[n][c]: as B (k=c, n=l15) or as A (m=n, k=c)
#pragma unroll
    for (int nt = 0; nt < 4; ++nt)
#pragma unroll
        for (int ks = 0; ks < 4; ++ks)
            bfrag[nt][ks] = *(const short8*)&h_lds[nt * 16 + l15][ks * 32 + q4 * 8];

#pragma unroll
    for (int ot = 0; ot < 6; ++ot) {
        int o0 = wave * 96 + ot * 16;                 // 16-row tile is purely Q, K, or V
        short8 af[4];                                 // w[o][c]: as A (m=o) or as B (n=o)
#pragma unroll
        for (int ks = 0; ks < 4; ++ks)
            af[ks] = ldg8(wq + (size_t)(o0 + l15) * 128 + ks * 32 + q4 * 8);

        if (o0 < 256) {               // Q or K: D[row=o(reg)][col=n=l15] -> [n][c] layout
            float bias[4];
#pragma unroll
            for (int r = 0; r < 4; ++r) bias[r] = qkv_b[o0 + q4 * 4 + r];
            float qs = (o0 < 128) ? QSCALE : 1.0f;
#pragma unroll
            for (int nt = 0; nt < 4; ++nt) {
                f32x4 acc = {0.f, 0.f, 0.f, 0.f};
#pragma unroll
                for (int ks = 0; ks < 4; ++ks)
                    acc = MFMA_BF16(af[ks], bfrag[nt][ks], acc);
                int n = n0 + nt * 16 + l15;
                unsigned short* dst = (o0 < 128) ? q_ws : k_ws;
                int oo = (o0 < 128) ? o0 : (o0 - 128);
                unsigned int lo = (unsigned int)f2bf((acc[0] + bias[0]) * qs) |
                                  ((unsigned int)f2bf((acc[1] + bias[1]) * qs) << 16);
                unsigned int hi = (unsigned int)f2bf((acc[2] + bias[2]) * qs) |
                                  ((unsigned int)f2bf((acc[3] + bias[3]) * qs) << 16);
                uint2 pk; pk.x = lo; pk.y = hi;
                *(uint2*)&dst[((size_t)(b * 4096 + n) << 7) + oo + q4 * 4] = pk;
            }
        } else {                      // V transposed: D[row=n(reg)][col=c=l15] -> [c][n]
            int c = o0 - 256 + l15;
            float vb = qkv_b[o0 + l15];
            unsigned short* vrow = v_ws + ((size_t)(b * 128 + c) << 12) + n0;
#pragma unroll
            for (int nt = 0; nt < 4; ++nt) {
                f32x4 acc = {0.f, 0.f, 0.f, 0.f};
#pragma unroll
                for (int ks = 0; ks < 4; ++ks)
                    acc = MFMA_BF16(bfrag[nt][ks], af[ks], acc);
                // n = nt*16 + q4*4 + r (4 consecutive) at fixed c -> packed 8B store
                unsigned int lo = (unsigned int)f2bf(acc[0] + vb) |
                                  ((unsigned int)f2bf(acc[1] + vb) << 16);
                unsigned int hi = (unsigned int)f2bf(acc[2] + vb) |
                                  ((unsigned int)f2bf(acc[3] + vb) << 16);
                uint2 pk; pk.x = lo; pk.y = hi;
                *(uint2*)&vrow[nt * 16 + q4 * 4] = pk;
            }
        }
    }
}

// ---------------- Kernel 3: flash attention partial (split-KV, 32x32 quadrants) ----
// block = 256 threads / 4 waves = (b, i-tile, chunk); chunk covers 1024 j.
// QK computes S^T: MFMA(A=kf, B=qf) -> D[j(reg)][i(lane)]; packed P_lds writes.
// PV: A = P[i][j], B = V^T[j][c]. acc[2] = O[i][c-half jh] (32 regs, no more).
// Staging: gload_lds dbuf. K swizzle: LDS(row, slot) = global(row, slot^(row&15)),
// slot=16B chunk of the 256B row. V swizzle: LDS(c, s8) = global(c, s8^(c&7)),
// s8 = 16B chunk of the 128B row. Both applied by pre-swizzling the per-lane
// GLOBAL source address; LDS dest stays linear (gload_lds requirement).
__global__ __launch_bounds__(256, 2) void k_attn_part(const unsigned short* __restrict__ q_ws,
                                                      const unsigned short* __restrict__ k_ws,
                                                      const unsigned short* __restrict__ v_ws,
                                                      unsigned short* __restrict__ o_part,
                                                      float* __restrict__ ml) {
    __shared__ unsigned short K0[64][128];      // 16 KB  (XOR-16 swizzled slots)
    __shared__ unsigned short K1[64][128];      // 16 KB
    __shared__ unsigned short V0[128][64];      // 16 KB  (XOR-8 swizzled slots)
    __shared__ unsigned short V1[128][64];      // 16 KB
    __shared__ unsigned short P_lds[64][72];    // [i][j], +8 pad  (9216 B)
    __shared__ float Lp[128];                   // row-sum exchange (512 B)

    const int tid   = threadIdx.x;
    const int chunk = blockIdx.x & 3;
    const int tile  = (blockIdx.x >> 2) & 63;
    const int b     = blockIdx.x >> 8;
    const int i0    = tile << 6;
    const int lane  = tid & 63, wave = tid >> 6;
    const int ih    = wave >> 1, jh = wave & 1;   // jh doubles as c-half in PV
    const int l31   = lane & 31, h = lane >> 5;

    // Q frags (pre-scaled by QSCALE): lane holds i=l31, k=c=ks*16+h*8+e
    short8 qf[8];
    {
        const unsigned short* qp =
            q_ws + ((size_t)(b * 4096 + i0 + ih * 32 + l31) << 7) + h * 8;
#pragma unroll
        for (int ks = 0; ks < 8; ++ks) qf[ks] = ldg8(qp + ks * 16);
    }

    f32x16 acc[2];                           // O[i(reg)][c = jh*64 + ct*32 + l31]
#pragma unroll
    for (int e = 0; e < 16; ++e) { acc[0][e] = 0.f; acc[1][e] = 0.f; }
    float l_run = 0.f;                       // this lane's 16-j partial per iter

    // K staging: lds chunk c = wave*256 + q*64 + lane (linear dest);
    // source chunk = (row, slot ^ (row&15)), row=c>>4, slot=c&15.  [R2/R3-verified]
    const unsigned short* kbase = k_ws + ((size_t)b << 19) + ((size_t)chunk << 17);
    int ksrcChunk[4];
#pragma unroll
    for (int q = 0; q < 4; ++q) {
        int c   = wave * 256 + q * 64 + lane;
        int row = c >> 4;
        ksrcChunk[q] = row * 16 + ((c & 15) ^ (row & 15));
    }
    // V staging: lds chunk L = (wave*4+q)*64 + lane; row = L>>3 = wave*32+q*8+(lane>>3),
    // dest s8 = lane&7; source s8 = (lane&7)^(lane>>3)  (row&7 == lane>>3).
    const unsigned short* vbase = v_ws + ((size_t)b << 19) +
        ((size_t)(wave * 32 + (lane >> 3)) << 12) +
        ((((lane & 7) ^ (lane >> 3))) << 3) + (chunk << 10);

#define STAGE(T, KD, VD)                                                              \
  do {                                                                                \
    _Pragma("unroll")                                                                 \
    for (int q = 0; q < 4; ++q)                                                       \
      gload16(kbase + (size_t)(T) * 8192 + ksrcChunk[q] * 8,                          \
              (char*)(&KD[0][0]) + wave * 4096 + q * 1024);                           \
    _Pragma("unroll")                                                                 \
    for (int q = 0; q < 4; ++q)                                                       \
      gload16(vbase + (size_t)q * 32768 + (T) * 64,                                   \
              (char*)(&VD[0][0]) + (wave * 4 + q) * 1024);                            \
  } while (0)

    const int krow = jh * 32 + l31;
    const int ksw  = krow & 15;
    const int vsw  = l31 & 7;                 // (jh*64+ct*32+l31) & 7 == l31 & 7

    // prologue: prefetch tile 0 -> buf0 (drained by first barrier; one-time cost)
    STAGE(0, K0, V0);

#define ATTN_ITER(IT, KR, VR, KP, VP)                                                 \
  do {                                                                                \
    __syncthreads(); /* A: buf(IT) loads visible (issued 1 iter ago); prev reads done */\
    if ((IT) < 15) STAGE((IT) + 1, KP, VP);   /* drains at NEXT barriers: hidden */   \
    f32x16 s; /* S^T quadrant: row j=(r&3)+8(r>>2)+4h (+jh*32), col i=l31 */          \
    _Pragma("unroll")                                                                 \
    for (int e = 0; e < 16; ++e) s[e] = 0.f;                                          \
    _Pragma("unroll")                                                                 \
    for (int ks = 0; ks < 8; ++ks) {                                                  \
      short8 kf = *(const short8*)&KR[krow][((ks * 2 + h) ^ ksw) << 3];               \
      s = MFMA32(kf, qf[ks], s);                                                      \
    }                                                                                 \
    float pv[16]; /* max-free base-2 softmax */                                       \
    _Pragma("unroll")                                                                 \
    for (int e = 0; e < 16; ++e) pv[e] = EXP2(fminf(s[e], 30.f));                     \
    l_run += (((pv[0] + pv[1]) + (pv[2] + pv[3])) +                                   \
              ((pv[4] + pv[5]) + (pv[6] + pv[7]))) +                                  \
             (((pv[8] + pv[9]) + (pv[10] + pv[11])) +                                 \
              ((pv[12] + pv[13]) + (pv[14] + pv[15])));                               \
    {                                                                                 \
      unsigned short* prow = &P_lds[ih * 32 + l31][jh * 32 + (h << 2)];               \
      _Pragma("unroll")                                                               \
      for (int rr = 0; rr < 4; ++rr) {                                                \
        uint2 pk;                                                                     \
        pk.x = cvtpk(pv[rr * 4 + 0], pv[rr * 4 + 1]);                                 \
        pk.y = cvtpk(pv[rr * 4 + 2], pv[rr * 4 + 3]);                                 \
        *(uint2*)(prow + rr * 8) = pk;                                                \
      }                                                                               \
    }                                                                                 \
    __syncthreads(); /* B: P visible; prefetch drain ~free (issued ~500cy ago) */     \
    _Pragma("unroll")                                                                 \
    for (int ks = 0; ks < 4; ++ks) {                                                  \
      short8 pf = *(const short8*)&P_lds[ih * 32 + l31][ks * 16 + h * 8];             \
      _Pragma("unroll")                                                               \
      for (int ct = 0; ct < 2; ++ct) {                                                \
        short8 vf = *(const short8*)                                                  \
            &VR[jh * 64 + ct * 32 + l31][((ks * 2 + h) ^ vsw) << 3];                  \
        acc[ct] = MFMA32(pf, vf, acc[ct]);                                            \
      }                                                                               \
    }                                                                                 \
  } while (0)

    for (int ib = 0; ib < 8; ++ib) {
        ATTN_ITER(ib * 2,     K0, V0, K1, V1);
        ATTN_ITER(ib * 2 + 1, K1, V1, K0, V0);
    }
#undef ATTN_ITER
#undef STAGE

    // epilogue: combine row sums (h via shfl, jh via LDS), normalize, store
    float l2 = l_run + __shfl_xor(l_run, 32);
    // lane (l31,h): h=0/h=1 cover disjoint j sets of row i=l31 in this wave's jh
    // half; shfl_xor(32) pairs them -> full 32-j contribution for row i.
    if (h == 0) Lp[jh * 64 + ih * 32 + l31] = l2;
    __syncthreads();

    size_t pbase = (size_t)((b * 64 + tile) * 4 + chunk) * 8192;
    float rl[16];
#pragma unroll
    for (int r = 0; r < 16; ++r) {
        int il = (r & 3) + ((r >> 2) << 3) + (h << 2);
        rl[r] = 1.0f / (Lp[ih * 32 + il] + Lp[64 + ih * 32 + il]);
    }
#pragma unroll
    for (int ct = 0; ct < 2; ++ct)
#pragma unroll
        for (int r = 0; r < 16; ++r) {
            int row = ih * 32 + (r & 3) + ((r >> 2) << 3) + (h << 2);
            o_part[pbase + (size_t)row * 128 + jh * 64 + ct * 32 + l31] =
                f2bf(acc[ct][r] * rl[r]);
        }
    if (tid < 64) {
        int mb = ((b * 64 + tile) * 4 + chunk) * 64;
        ml[mb + tid] = __log2f(Lp[tid] + Lp[64 + tid]);
    }
}

// ---------------- Kernel 4: merge partials + proj GEMM + bias + residual ----------
__global__ __launch_bounds__(256) void k_merge_proj(const unsigned short* __restrict__ o_part,
                                                    const float* __restrict__ ml,
                                                    const float* __restrict__ x,
                                                    const unsigned short* __restrict__ wp,
                                                    const float* __restrict__ proj_b,
                                                    float* __restrict__ out) {
    __shared__ unsigned short O_lds[64][136];
    __shared__ float wgt[64][4];
    const int tid  = threadIdx.x;
    const int b    = blockIdx.x >> 6;
    const int tile = blockIdx.x & 63;
    const int i0   = tile << 6;
    const int lane = tid & 63, wave = tid >> 6;
    const int l15  = lane & 15, q4 = lane >> 4;
    const int tb   = (b * 64 + tile) * 4;

    if (tid < 64) {
        float m0 = ml[(tb + 0) * 64 + tid], m1 = ml[(tb + 1) * 64 + tid];
        float m2 = ml[(tb + 2) * 64 + tid], m3 = ml[(tb + 3) * 64 + tid];
        float M = fmaxf(fmaxf(m0, m1), fmaxf(m2, m3));
        float w0 = EXP2(m0 - M), w1 = EXP2(m1 - M), w2 = EXP2(m2 - M), w3 = EXP2(m3 - M);
        float rW = 1.0f / (w0 + w1 + w2 + w3);
        wgt[tid][0] = w0 * rW; wgt[tid][1] = w1 * rW;
        wgt[tid][2] = w2 * rW; wgt[tid][3] = w3 * rW;
    }
    __syncthreads();

    {   // weighted merge: thread t -> row n=t>>2, 32-c quarter q=t&3
        int n = tid >> 2, q = tid & 3;
        float w[4];
#pragma unroll
        for (int ch = 0; ch < 4; ++ch) w[ch] = wgt[n][ch];
#pragma unroll
        for (int g = 0; g < 4; ++g) {             // 8 c per group
            float acc[8];
#pragma unroll
            for (int e = 0; e < 8; ++e) acc[e] = 0.f;
#pragma unroll
            for (int ch = 0; ch < 4; ++ch) {
                const unsigned short* p =
                    o_part + (size_t)(tb + ch) * 8192 + (size_t)n * 128 + q * 32 + g * 8;
                uint4 v = *(const uint4*)p;
                float wc = w[ch];
                acc[0] += wc * bf2f(v.x & 0xFFFF); acc[1] += wc * bf2f(v.x >> 16);
                acc[2] += wc * bf2f(v.y & 0xFFFF); acc[3] += wc * bf2f(v.y >> 16);
                acc[4] += wc * bf2f(v.z & 0xFFFF); acc[5] += wc * bf2f(v.z >> 16);
                acc[6] += wc * bf2f(v.w & 0xFFFF); acc[7] += wc * bf2f(v.w >> 16);
            }
            uint4 pk;
            pk.x = (unsigned int)f2bf(acc[0]) | ((unsigned int)f2bf(acc[1]) << 16);
            pk.y = (unsigned int)f2bf(acc[2]) | ((unsigned int)f2bf(acc[3]) << 16);
            pk.z = (unsigned int)f2bf(acc[4]) | ((unsigned int)f2bf(acc[5]) << 16);
            pk.w = (unsigned int)f2bf(acc[6]) | ((unsigned int)f2bf(acc[7]) << 16);
            *(uint4*)&O_lds[n][q * 32 + g * 8] = pk;
        }
    }
    __syncthreads();

    // proj GEMM: out[o][n] = sum_c proj_w[o][c] * O[n][c] + proj_b + x
    short8 bfrag[4][4];
#pragma unroll
    for (int nt = 0; nt < 4; ++nt)
#pragma unroll
        for (int ks = 0; ks < 4; ++ks)
            bfrag[nt][ks] = *(const short8*)&O_lds[nt * 16 + l15][ks * 32 + q4 * 8];

#pragma unroll
    for (int ot = 0; ot < 2; ++ot) {
        int o0 = wave * 32 + ot * 16;
        short8 af[4];
#pragma unroll
        for (int ks = 0; ks < 4; ++ks)
            af[ks] = ldg8(wp + (size_t)(o0 + l15) * 128 + ks * 32 + q4 * 8);
        float pb[4];
#pragma unroll
        for (int r = 0; r < 4; ++r) pb[r] = proj_b[o0 + q4 * 4 + r];

#pragma unroll
        for (int nt = 0; nt < 4; ++nt) {
            f32x4 acc = {0.f, 0.f, 0.f, 0.f};
#pragma unroll
            for (int ks = 0; ks < 4; ++ks)
                acc = MFMA_BF16(af[ks], bfrag[nt][ks], acc);
#pragma unroll
            for (int r = 0; r < 4; ++r) {
                size_t idx = ((size_t)(b * 128 + o0 + q4 * 4 + r) << 12) + i0 + nt * 16 + l15;
                out[idx] = x[idx] + acc[r] + pb[r];
            }
        }
    }
}

// ---------------- launch ----------------
extern "C" void kernel_launch(void* const* d_in, const int* in_sizes, int n_in,
                              void* d_out, int out_size, void* d_ws, size_t ws_size,
                              hipStream_t stream) {
    const float* x      = (const float*)d_in[0];
    const float* gn_w   = (const float*)d_in[1];
    const float* gn_b   = (const float*)d_in[2];
    const float* qkv_w  = (const float*)d_in[3];
    const float* qkv_b  = (const float*)d_in[4];
    const float* proj_w = (const float*)d_in[5];
    const float* proj_b = (const float*)d_in[6];
    float* out = (float*)d_out;

    char* ws = (char*)d_ws;
    float* sums           = (float*)ws;                              // 512 B (zeroed below)
    unsigned short* wq    = (unsigned short*)(ws + 4096);            // 96 KB
    unsigned short* wp    = (unsigned short*)(ws + 4096 + 98304);    // 32 KB
    unsigned short* q_ws  = (unsigned short*)(ws + ((size_t)1  << 20));  // 8 MB
    unsigned short* k_ws  = (unsigned short*)(ws + ((size_t)9  << 20));  // 8 MB
    unsigned short* v_ws  = (unsigned short*)(ws + ((size_t)17 << 20));  // 8 MB
    unsigned short* o_part= (unsigned short*)(ws + ((size_t)25 << 20));  // 32 MB
    float* ml             = (float*)(ws + ((size_t)57 << 20));           // 512 KB

    hipMemsetAsync(sums, 0, 512, stream);
    k_pre<<<1088, 256, 0, stream>>>(x, sums, qkv_w, proj_w, wq, wp);
    k_qkv<<<512, 256, 0, stream>>>(x, sums, gn_w, gn_b, wq, qkv_b, q_ws, k_ws, v_ws);
    k_attn_part<<<2048, 256, 0, stream>>>(q_ws, k_ws, v_ws, o_part, ml);
    k_merge_proj<<<512, 256, 0, stream>>>(o_part, ml, x, wp, proj_b, out);
}